// Round 1
// baseline (212.910 us; speedup 1.0000x reference)
//
#include <hip/hip_runtime.h>
#include <stdint.h>

// Shapes (fixed by the problem)
#define Bn 256
#define Un 128
#define Pn 64
#define Hn 768
#define Ototal 192   // 128 row-logit outputs + 64 col-logit outputs
#define KC 16        // split-K chunks in phase B (K=8192 -> 512 each)

typedef short s4v __attribute__((ext_vector_type(4)));
typedef short s8v __attribute__((ext_vector_type(8)));
typedef float f4v __attribute__((ext_vector_type(4)));

__device__ __forceinline__ short f2bf(float x) {
  union { float f; uint32_t u; } c; c.f = x;
  uint32_t r = (c.u + 0x7fffu + ((c.u >> 16) & 1u)) >> 16;  // RNE
  return (short)(r & 0xffffu);
}

// ---------------------------------------------------------------------------
// Kernel 1: pack weights into bf16 W'[o][k], o<128: w_utt[o,i,j]; o>=128:
// w_pheno[o-128, j, i]  (k = i*64 + j) so both logit einsums share one GEMM.
// ---------------------------------------------------------------------------
__global__ void __launch_bounds__(256) convW(const float* __restrict__ w_utt,
                                             const float* __restrict__ w_ph,
                                             ushort* __restrict__ Wbf) {
  int idx = blockIdx.x * 256 + threadIdx.x;     // 0 .. 192*8192-1
  int o = idx >> 13;
  int k = idx & 8191;
  float v;
  if (o < Un) {
    v = w_utt[(size_t)o * 8192 + k];            // contiguous
  } else {
    int oc = o - Un;
    int i = k >> 6, j = k & 63;
    v = w_ph[((size_t)oc * Pn + j) * Un + i];
  }
  Wbf[idx] = (ushort)f2bf(v);
}

// ---------------------------------------------------------------------------
// Kernel 2: per-batch cosine-sim matrix.
// c[b,i,j] = (u_i . p_j) * inu_i * inp_j   (norms factor out of the dot!)
// One block per batch, 512 threads = 8 waves; wave w owns i-tile w (16 rows),
// all 4 j-tiles. Single pass over u[b],p[b]: sumsq accumulated from the same
// registers that feed the bf16 LDS staging.
// ---------------------------------------------------------------------------
__global__ void __launch_bounds__(512) phaseA(const float* __restrict__ utt,
                                              const float* __restrict__ ph,
                                              ushort* __restrict__ Cbf) {
  const int b = blockIdx.x;
  const int t = threadIdx.x;
  const int w = t >> 6, l = t & 63;

  __shared__ short uA[Un * 32];   // [i][h-chunk] bf16
  __shared__ short pB[Pn * 32];   // [j][h-chunk] bf16
  __shared__ float s_inu[Un];
  __shared__ float s_inp[Pn];

  const int r0   = t >> 3;        // 0..63
  const int hoff = (t & 7) * 4;   // 0,4,..,28
  const size_t rstride = (size_t)Bn * Hn;  // 196608: row stride for both u,p

  const float* ub = utt + (size_t)b * Hn;  // u[b,i,h] = ub[i*rstride + h]
  const float* pb = ph  + (size_t)b * Hn;  // p[b,j,h] = pb[j*rstride + h]

  float4 ru0, ru1, rp0;
  float ssu0 = 0.f, ssu1 = 0.f, ssp0 = 0.f;

  f4v zero4 = {0.f, 0.f, 0.f, 0.f};
  f4v acc[4] = {zero4, zero4, zero4, zero4};

  // preload chunk 0
  {
    const float* u0 = ub + (size_t)r0 * rstride + hoff;
    ru0 = *(const float4*)(u0);
    ru1 = *(const float4*)(u0 + (size_t)64 * rstride);
    rp0 = *(const float4*)(pb + (size_t)r0 * rstride + hoff);
  }

  const int m  = l & 15;
  const int ko = (l >> 4) * 8;
  const short* aptr = &uA[(16 * w + m) * 32 + ko];

  for (int c = 0; c < 24; ++c) {
    __syncthreads();  // previous chunk's MFMA reads done before overwrite
    // fused sumsq + bf16 convert + LDS store
    ssu0 += ru0.x*ru0.x + ru0.y*ru0.y + ru0.z*ru0.z + ru0.w*ru0.w;
    ssu1 += ru1.x*ru1.x + ru1.y*ru1.y + ru1.z*ru1.z + ru1.w*ru1.w;
    ssp0 += rp0.x*rp0.x + rp0.y*rp0.y + rp0.z*rp0.z + rp0.w*rp0.w;
    s4v a0 = {f2bf(ru0.x), f2bf(ru0.y), f2bf(ru0.z), f2bf(ru0.w)};
    s4v a1 = {f2bf(ru1.x), f2bf(ru1.y), f2bf(ru1.z), f2bf(ru1.w)};
    s4v p0 = {f2bf(rp0.x), f2bf(rp0.y), f2bf(rp0.z), f2bf(rp0.w)};
    *(s4v*)&uA[(size_t)r0 * 32 + hoff]        = a0;
    *(s4v*)&uA[((size_t)r0 + 64) * 32 + hoff] = a1;
    *(s4v*)&pB[(size_t)r0 * 32 + hoff]        = p0;
    __syncthreads();
    // prefetch next chunk into registers (overlaps with MFMA below)
    if (c < 23) {
      const int hb = (c + 1) * 32 + hoff;
      const float* u0 = ub + (size_t)r0 * rstride + hb;
      ru0 = *(const float4*)(u0);
      ru1 = *(const float4*)(u0 + (size_t)64 * rstride);
      rp0 = *(const float4*)(pb + (size_t)r0 * rstride + hb);
    }
    s8v af = *(const s8v*)aptr;
#pragma unroll
    for (int jt = 0; jt < 4; ++jt) {
      s8v bf = *(const s8v*)&pB[(16 * jt + m) * 32 + ko];
      acc[jt] = __builtin_amdgcn_mfma_f32_16x16x32_bf16(af, bf, acc[jt], 0, 0, 0);
    }
  }

  // finish row sumsq: 8 consecutive lanes share a row
  ssu0 += __shfl_xor(ssu0, 4); ssu0 += __shfl_xor(ssu0, 2); ssu0 += __shfl_xor(ssu0, 1);
  ssu1 += __shfl_xor(ssu1, 4); ssu1 += __shfl_xor(ssu1, 2); ssu1 += __shfl_xor(ssu1, 1);
  ssp0 += __shfl_xor(ssp0, 4); ssp0 += __shfl_xor(ssp0, 2); ssp0 += __shfl_xor(ssp0, 1);
  if ((t & 7) == 0) {
    int row = t >> 3;                       // 0..63
    s_inu[row]      = 1.f / fmaxf(sqrtf(ssu0), 1e-8f);
    s_inu[row + 64] = 1.f / fmaxf(sqrtf(ssu1), 1e-8f);
    s_inp[row]      = 1.f / fmaxf(sqrtf(ssp0), 1e-8f);
  }
  __syncthreads();

  // epilogue: scale by inu*inp, store bf16 C[b][i][j]
  // D layout (verified m89/m91): col = lane&15, row = (lane>>4)*4 + reg
  const int cl = l & 15;
  const int rq = (l >> 4) * 4;
#pragma unroll
  for (int jt = 0; jt < 4; ++jt) {
    int j = 16 * jt + cl;
    float sj = s_inp[j];
#pragma unroll
    for (int r = 0; r < 4; ++r) {
      int il = 16 * w + rq + r;
      float v = acc[jt][r] * s_inu[il] * sj;
      Cbf[((size_t)b * Un + il) * Pn + j] = (ushort)f2bf(v);
    }
  }
}

// ---------------------------------------------------------------------------
// Kernel 3: logits GEMM, M=256 batches, N=192 outputs, K=8192, split-K.
// grid = (kc=16, mt=4, nt=3); 64x64 tile per block; partial[kc][b][o] fp32.
// ---------------------------------------------------------------------------
__global__ void __launch_bounds__(256) phaseB(const ushort* __restrict__ Cbf,
                                              const ushort* __restrict__ Wbf,
                                              float* __restrict__ partial) {
  const int kc = blockIdx.x;
  const int mt = blockIdx.y;
  const int nt = blockIdx.z;
  const int t = threadIdx.x;
  const int w = t >> 6, l = t & 63;

  __shared__ short Ab[64 * 32];
  __shared__ short Bb[64 * 32];

  const int row = t >> 2;          // 0..63
  const int ko8 = (t & 3) * 8;

  f4v zero4 = {0.f, 0.f, 0.f, 0.f};
  f4v acc[4] = {zero4, zero4, zero4, zero4};

  const ushort* Ag = Cbf + (size_t)(mt * 64 + row) * 8192 + kc * 512 + ko8;
  const ushort* Bg = Wbf + (size_t)(nt * 64 + row) * 8192 + kc * 512 + ko8;
  const int m  = l & 15;
  const int ko = (l >> 4) * 8;

  for (int c = 0; c < 16; ++c) {
    s8v av = *(const s8v*)(Ag + c * 32);   // issued before barrier: overlap
    s8v bv = *(const s8v*)(Bg + c * 32);
    __syncthreads();
    *(s8v*)&Ab[row * 32 + ko8] = av;
    *(s8v*)&Bb[row * 32 + ko8] = bv;
    __syncthreads();
    s8v af = *(const s8v*)&Ab[(16 * w + m) * 32 + ko];
#pragma unroll
    for (int jt = 0; jt < 4; ++jt) {
      s8v bf = *(const s8v*)&Bb[(16 * jt + m) * 32 + ko];
      acc[jt] = __builtin_amdgcn_mfma_f32_16x16x32_bf16(af, bf, acc[jt], 0, 0, 0);
    }
  }

  const int rq = (l >> 4) * 4;
#pragma unroll
  for (int jt = 0; jt < 4; ++jt) {
    int og = nt * 64 + 16 * jt + (l & 15);
#pragma unroll
    for (int r = 0; r < 4; ++r) {
      int bg = mt * 64 + 16 * w + rq + r;
      partial[((size_t)kc * Bn + bg) * Ototal + og] = acc[jt][r];
    }
  }
}

// ---------------------------------------------------------------------------
// Kernel 4: reduce split-K partials + bias + dual-group softmax.
// 192 threads: t<128 -> row softmax (waves 0,1), t>=128 -> col softmax (wave 2)
// ---------------------------------------------------------------------------
__global__ void __launch_bounds__(192) phaseC(const float* __restrict__ partial,
                                              const float* __restrict__ b_utt,
                                              const float* __restrict__ b_ph,
                                              float* __restrict__ out) {
  const int b = blockIdx.x;
  const int t = threadIdx.x;      // 0..191
  const int w = t >> 6, l = t & 63;

  float v = 0.f;
#pragma unroll
  for (int kc = 0; kc < KC; ++kc)
    v += partial[((size_t)kc * Bn + b) * Ototal + t];
  v += (t < Un) ? b_utt[t] : b_ph[t - Un];

  __shared__ float red[3];
  float mx = v;
  for (int o = 32; o >= 1; o >>= 1) mx = fmaxf(mx, __shfl_xor(mx, o));
  if (l == 0) red[w] = mx;
  __syncthreads();
  float gmax = (t < Un) ? fmaxf(red[0], red[1]) : red[2];
  float e = expf(v - gmax);
  float s = e;
  for (int o = 32; o >= 1; o >>= 1) s += __shfl_xor(s, o);
  __syncthreads();
  if (l == 0) red[w] = s;
  __syncthreads();
  float gs = (t < Un) ? (red[0] + red[1]) : red[2];
  float r = e / gs;
  if (t < Un) out[(size_t)b * Un + t] = r;
  else        out[(size_t)Bn * Un + (size_t)b * Pn + (t - Un)] = r;
}

// ---------------------------------------------------------------------------
extern "C" void kernel_launch(void* const* d_in, const int* in_sizes, int n_in,
                              void* d_out, int out_size, void* d_ws, size_t ws_size,
                              hipStream_t stream) {
  const float* utt   = (const float*)d_in[0];  // [128,256,768]
  const float* ph    = (const float*)d_in[1];  // [64,256,768]
  const float* w_utt = (const float*)d_in[2];  // [128,128,64]
  const float* b_utt = (const float*)d_in[3];  // [128]
  const float* w_ph  = (const float*)d_in[4];  // [64,64,128]
  const float* b_ph  = (const float*)d_in[5];  // [64]

  char* ws = (char*)d_ws;
  ushort* Cbf     = (ushort*)(ws);                 // 256*128*64*2  = 4 MiB
  ushort* Wbf     = (ushort*)(ws + 4194304);       // 192*8192*2   = 3 MiB
  float*  partial = (float*)(ws + 7340032);        // 16*256*192*4 = 3 MiB

  convW <<<dim3(6144), dim3(256), 0, stream>>>(w_utt, w_ph, Wbf);
  phaseA<<<dim3(Bn),   dim3(512), 0, stream>>>(utt, ph, Cbf);
  phaseB<<<dim3(KC, 4, 3), dim3(256), 0, stream>>>(Cbf, Wbf, partial);
  phaseC<<<dim3(Bn),   dim3(192), 0, stream>>>(partial, b_utt, b_ph, (float*)d_out);
}